// Round 5
// baseline (5669.156 us; speedup 1.0000x reference)
//
#include <hip/hip_runtime.h>
#include <hip/hip_bf16.h>
#include <math.h>

// ---------------- constants ----------------
constexpr int L_ = 2, D_ = 512, H_ = 8, DH_ = 64, HI_ = 4, F_ = 2048, E_ = 8;
constexpr int V_ = 32000, S_ = 1024, B_ = 2, K_ = 256;
constexpr int BS_ = B_ * S_;            // 2048 token rows
constexpr float EPS_ = 1e-5f;
constexpr int NPAD_ = 4608;             // padded MoE entries (<= 4096 + 8*63, rounded)
constexpr int CHUNKS_ = NPAD_ / 64;     // 72

#define DEV __device__ __forceinline__

DEV float wave_sum(float v) { for (int m = 1; m < 64; m <<= 1) v += __shfl_xor(v, m, 64); return v; }
DEV float wave_max(float v) { for (int m = 1; m < 64; m <<= 1) v = fmaxf(v, __shfl_xor(v, m, 64)); return v; }
DEV unsigned f2key(float f) { unsigned b = __float_as_uint(f); return (b & 0x80000000u) ? ~b : (b | 0x80000000u); }
DEV float gelu_tanh(float x) {
  float x3 = x * x * x;
  return 0.5f * x * (1.0f + tanhf(0.79788456080286535588f * (x + 0.044715f * x3)));
}

// ---------------- embedding ----------------
__global__ void embed_k(const int* __restrict__ ids, const float* __restrict__ tok,
                        const float* __restrict__ pos, float* __restrict__ x) {
  int row = blockIdx.x;             // b*S + s
  int s = row % S_;
  int id = ids[row];
  const float* tp = tok + (size_t)id * D_;
  const float* pp = pos + (size_t)s * D_;
  float* xp = x + (size_t)row * D_;
  for (int d = threadIdx.x; d < D_; d += blockDim.x) xp[d] = tp[d] + pp[d];
}

// ---------------- layernorm (row of 512) ----------------
__global__ __launch_bounds__(256) void ln_k(const float* __restrict__ in, const float* __restrict__ g,
                                            const float* __restrict__ b, float* __restrict__ out) {
  int row = blockIdx.x, tid = threadIdx.x;
  const float* xr = in + (size_t)row * D_;
  float v0 = xr[tid], v1 = xr[tid + 256];
  __shared__ float shm[4];
  int wid = tid >> 6, lane = tid & 63;
  float s = wave_sum(v0 + v1);
  if (lane == 0) shm[wid] = s;
  __syncthreads();
  float mu = (shm[0] + shm[1] + shm[2] + shm[3]) * (1.0f / D_);
  __syncthreads();
  float d0 = v0 - mu, d1 = v1 - mu;
  float q = wave_sum(d0 * d0 + d1 * d1);
  if (lane == 0) shm[wid] = q;
  __syncthreads();
  float var = (shm[0] + shm[1] + shm[2] + shm[3]) * (1.0f / D_);
  float rs = rsqrtf(var + EPS_);
  float* op = out + (size_t)row * D_;
  op[tid]       = d0 * rs * g[tid]       + b[tid];
  op[tid + 256] = d1 * rs * g[tid + 256] + b[tid + 256];
}

// ---------------- indexer scores (causal only) ----------------
__global__ __launch_bounds__(256) void idxsc_k(const float* __restrict__ qi, const float* __restrict__ ki,
                                               const float* __restrict__ hw, float* __restrict__ sc) {
  int row = blockIdx.x;             // b*S + q
  int b = row / S_, q = row % S_;
  int tid = threadIdx.x;
  __shared__ float qs[256];
  qs[tid] = qi[(size_t)row * 256 + tid];
  __syncthreads();
  float w0 = hw[0], w1 = hw[1], w2 = hw[2], w3 = hw[3];
  float* srow = sc + (size_t)row * S_;
  for (int k = tid; k <= q; k += 256) {
    const float* kr = ki + (size_t)(b * S_ + k) * 256;
    float d0 = 0, d1 = 0, d2 = 0, d3 = 0;
#pragma unroll 8
    for (int i = 0; i < 64; ++i) {
      d0 += qs[i]       * kr[i];
      d1 += qs[64 + i]  * kr[64 + i];
      d2 += qs[128 + i] * kr[128 + i];
      d3 += qs[192 + i] * kr[192 + i];
    }
    srow[k] = w0 * fmaxf(d0, 0.f) + w1 * fmaxf(d1, 0.f) + w2 * fmaxf(d2, 0.f) + w3 * fmaxf(d3, 0.f);
  }
}

// ---------------- exact K-th largest per causal row ----------------
__global__ __launch_bounds__(256) void thr_k(const float* __restrict__ sc, float* __restrict__ thr) {
  int row = blockIdx.x, tid = threadIdx.x;
  int q = row % S_, n = q + 1;
  if (n <= K_) { if (tid == 0) thr[row] = -3.0e38f; return; }
  const float* srow = sc + (size_t)row * S_;
  __shared__ float sh[4];
  int wid = tid >> 6, lane = tid & 63;
  unsigned ans = 0u;
  for (int bit = 31; bit >= 0; --bit) {
    unsigned cand = ans | (1u << bit);
    int c = 0;
    for (int k = tid; k < n; k += 256) c += (f2key(srow[k]) >= cand) ? 1 : 0;
    float t = wave_sum((float)c);
    if (lane == 0) sh[wid] = t;
    __syncthreads();
    float total = sh[0] + sh[1] + sh[2] + sh[3];
    __syncthreads();
    if (total >= (float)K_) ans = cand;
  }
  if (tid == 0) {
    unsigned b = (ans & 0x80000000u) ? (ans ^ 0x80000000u) : ~ans;
    thr[row] = __uint_as_float(b);
  }
}

// ---------------- attention: one (b,h,q) per 64-thread block ----------------
__global__ __launch_bounds__(64) void attn_k(const float* __restrict__ qb, const float* __restrict__ kb,
                                             const float* __restrict__ vb, const float* __restrict__ sc,
                                             const float* __restrict__ thr, float* __restrict__ out) {
  int gid = blockIdx.x;
  int q = gid % S_;
  int bh = gid / S_;
  int h = bh % H_, b = bh / H_;
  int row = b * S_ + q;
  int tid = threadIdx.x;
  __shared__ float p[S_];
  __shared__ float qs[DH_];
  qs[tid] = qb[(size_t)row * D_ + h * DH_ + tid];
  __syncthreads();
  float th = thr[row];
  const float* srow = sc + (size_t)row * S_;
  float mx = -3.0e38f;
  for (int k = tid; k <= q; k += 64) {
    float lg = -3.0e38f;
    if (srow[k] >= th) {
      const float* kr = kb + (size_t)(b * S_ + k) * D_ + h * DH_;
      float d = 0.f;
#pragma unroll
      for (int i = 0; i < DH_; ++i) d += qs[i] * kr[i];
      lg = d * 0.125f;   // 1/sqrt(64)
    }
    p[k] = lg;
    mx = fmaxf(mx, lg);
  }
  mx = wave_max(mx);
  __syncthreads();
  float sum = 0.f;
  for (int k = tid; k <= q; k += 64) {
    float lg = p[k];
    float e = (lg < -1.0e37f) ? 0.f : __expf(lg - mx);
    p[k] = e;
    sum += e;
  }
  sum = wave_sum(sum);
  __syncthreads();
  float inv = 1.0f / sum;
  float acc = 0.f;
  for (int k = 0; k <= q; ++k) {
    float pv = p[k];
    if (pv != 0.f) acc += pv * vb[(size_t)(b * S_ + k) * D_ + h * DH_ + tid];
  }
  out[(size_t)row * D_ + h * DH_ + tid] = acc * inv;
}

// ---------------- router: softmax over 8, top-2 renormalized ----------------
__global__ void router_k(const float* __restrict__ m, const float* __restrict__ rw,
                         const float* __restrict__ rb, int* __restrict__ counts,
                         int* __restrict__ gi2, float* __restrict__ gv2) {
  int t = blockIdx.x * blockDim.x + threadIdx.x;
  if (t >= BS_) return;
  float lg[E_];
#pragma unroll
  for (int e = 0; e < E_; ++e) lg[e] = rb[e];
  const float* mr = m + (size_t)t * D_;
  for (int d = 0; d < D_; ++d) {
    float mv = mr[d];
    const float* wr = rw + (size_t)d * E_;
#pragma unroll
    for (int e = 0; e < E_; ++e) lg[e] += mv * wr[e];
  }
  float mx = lg[0];
#pragma unroll
  for (int e = 1; e < E_; ++e) mx = fmaxf(mx, lg[e]);
  float p[E_], s = 0.f;
#pragma unroll
  for (int e = 0; e < E_; ++e) { p[e] = __expf(lg[e] - mx); s += p[e]; }
  float inv = 1.f / s;
#pragma unroll
  for (int e = 0; e < E_; ++e) p[e] *= inv;
  int i0 = 0;
#pragma unroll
  for (int e = 1; e < E_; ++e) if (p[e] > p[i0]) i0 = e;
  int i1 = (i0 == 0) ? 1 : 0;
#pragma unroll
  for (int e = 0; e < E_; ++e) if (e != i0 && p[e] > p[i1]) i1 = e;
  float g0 = p[i0], g1 = p[i1], gs = 1.f / (g0 + g1);
  gi2[t * 2] = i0; gi2[t * 2 + 1] = i1;
  gv2[t * 2] = g0 * gs; gv2[t * 2 + 1] = g1 * gs;
  atomicAdd(&counts[i0], 1);
  atomicAdd(&counts[i1], 1);
}

__global__ void prefix_k(const int* __restrict__ counts, int* __restrict__ offp, int* __restrict__ fill) {
  if (threadIdx.x == 0) {
    int o = 0;
    for (int e = 0; e < E_; ++e) { offp[e] = o; o += ((counts[e] + 63) >> 6) << 6; }
    offp[E_] = o;
  }
  if (threadIdx.x < E_) fill[threadIdx.x] = 0;
}

__global__ void initent_k(const int* __restrict__ offp, int* __restrict__ toklist, int* __restrict__ explist) {
  int i = blockIdx.x * blockDim.x + threadIdx.x;
  if (i >= NPAD_) return;
  toklist[i] = -1;
  int e = 0;
#pragma unroll
  for (int j = 0; j < E_; ++j) if (i >= offp[j]) e = j;
  explist[i] = e;
}

__global__ void fillent_k(const int* __restrict__ gi2, const float* __restrict__ gv2,
                          const int* __restrict__ offp, int* __restrict__ fill,
                          int* __restrict__ toklist, float* __restrict__ gatelist) {
  int t = blockIdx.x * blockDim.x + threadIdx.x;
  if (t >= BS_) return;
  for (int j = 0; j < 2; ++j) {
    int e = gi2[t * 2 + j];
    int pos = atomicAdd(&fill[e], 1);
    int idx = offp[e] + pos;
    toklist[idx] = t;
    gatelist[idx] = gv2[t * 2 + j];
  }
}

// ---------------- generic 64x64x16 fp32 tiled GEMM ----------------
// MODE 0: out = A@W + bias (+res)        (f32 out)
// MODE 1: h1 = gelu(gather(A)@W1[e]+b1)  (MoE stage 1)
// MODE 2: x[tok] += gate*(A@W2[e]+b2)    (MoE stage 2, atomic scatter)
template <int MODE>
__global__ __launch_bounds__(256) void gemm_k(
    const float* __restrict__ A, const float* __restrict__ W,
    const float* __restrict__ bias, const float* __restrict__ res,
    float* __restrict__ out,
    int M, int N, int Kd,
    const int* __restrict__ toklist, const float* __restrict__ gatelist,
    const int* __restrict__ explist) {
  __shared__ float As[16][65];
  __shared__ float Bs[16][65];
  int bm0 = blockIdx.x * 64;
  int bn0 = blockIdx.y * 64;
  int tid = threadIdx.x;
  int tx = tid & 15, ty = tid >> 4;

  const float* Wp = W;
  const float* biasp = bias;
  if (MODE == 1) { int e = explist[bm0]; Wp = W + (size_t)e * D_ * F_; biasp = bias + (size_t)e * F_; }
  if (MODE == 2) { int e = explist[bm0]; Wp = W + (size_t)e * F_ * D_; biasp = bias + (size_t)e * D_; }

  int lda = (MODE == 1) ? D_ : Kd;
  int arow[4];
#pragma unroll
  for (int i = 0; i < 4; ++i) {
    int ml = (i * 256 + tid) >> 4;
    arow[i] = (MODE == 1) ? toklist[bm0 + ml] : (bm0 + ml);
  }

  float c[4][4] = {};
  for (int k0 = 0; k0 < Kd; k0 += 16) {
#pragma unroll
    for (int i = 0; i < 4; ++i) {
      int idx = i * 256 + tid;
      int ml = idx >> 4, kk = idx & 15;
      float v = 0.f;
      if (MODE != 1 || arow[i] >= 0) v = A[(size_t)arow[i] * lda + k0 + kk];
      As[kk][ml] = v;
    }
#pragma unroll
    for (int i = 0; i < 4; ++i) {
      int idx = i * 256 + tid;
      int kk = idx >> 6, nn = idx & 63;
      Bs[kk][nn] = Wp[(size_t)(k0 + kk) * N + bn0 + nn];
    }
    __syncthreads();
#pragma unroll
    for (int kk = 0; kk < 16; ++kk) {
      float a[4], bb[4];
#pragma unroll
      for (int i = 0; i < 4; ++i) a[i] = As[kk][ty + 16 * i];
#pragma unroll
      for (int j = 0; j < 4; ++j) bb[j] = Bs[kk][tx + 16 * j];
#pragma unroll
      for (int i = 0; i < 4; ++i)
#pragma unroll
        for (int j = 0; j < 4; ++j) c[i][j] += a[i] * bb[j];
    }
    __syncthreads();
  }

#pragma unroll
  for (int i = 0; i < 4; ++i) {
    int ml = ty + 16 * i;
    int m = bm0 + ml;
#pragma unroll
    for (int j = 0; j < 4; ++j) {
      int n = bn0 + tx + 16 * j;
      float v = c[i][j] + biasp[n];
      if (MODE == 0) {
        float r = res ? res[(size_t)m * N + n] : 0.f;
        out[(size_t)m * N + n] = v + r;
      } else if (MODE == 1) {
        out[(size_t)m * (size_t)N + n] = gelu_tanh(v);
      } else if (MODE == 2) {
        int tok = toklist[m];
        if (tok >= 0) atomicAdd(&out[(size_t)tok * D_ + n], gatelist[m] * v);
      }
    }
  }
}

// ---------------- host ----------------
extern "C" void kernel_launch(void* const* d_in, const int* in_sizes, int n_in,
                              void* d_out, int out_size, void* d_ws, size_t ws_size,
                              hipStream_t stream) {
  const int*   ids  = (const int*)d_in[0];
  const float* tok  = (const float*)d_in[1];
  const float* pos  = (const float*)d_in[2];
  const float* ln1g = (const float*)d_in[3];
  const float* ln1b = (const float*)d_in[4];
  const float* iqw  = (const float*)d_in[5];
  const float* iqb  = (const float*)d_in[6];
  const float* ikw  = (const float*)d_in[7];
  const float* ikb  = (const float*)d_in[8];
  const float* ihw  = (const float*)d_in[9];
  const float* wq   = (const float*)d_in[10];
  const float* bq   = (const float*)d_in[11];
  const float* wk   = (const float*)d_in[12];
  const float* bk   = (const float*)d_in[13];
  const float* wv   = (const float*)d_in[14];
  const float* bv   = (const float*)d_in[15];
  const float* wo   = (const float*)d_in[16];
  const float* bo   = (const float*)d_in[17];
  const float* ln2g = (const float*)d_in[18];
  const float* ln2b = (const float*)d_in[19];
  const float* rw   = (const float*)d_in[20];
  const float* rb   = (const float*)d_in[21];
  const float* ew1  = (const float*)d_in[22];
  const float* eb1  = (const float*)d_in[23];
  const float* ew2  = (const float*)d_in[24];
  const float* eb2  = (const float*)d_in[25];
  const float* lnfg = (const float*)d_in[26];
  const float* lnfb = (const float*)d_in[27];
  const float* outw = (const float*)d_in[28];
  const float* outbs = (const float*)d_in[29];
  float* y = (float*)d_out;   // reference output is FLOAT32 (out_npz 243.6MB == f32*0.93)

  // --- scratch layout ---
  // d_ws holds only x, h, mbuf + small arrays (~12.7MB) to be safe against a
  // small ws_size. All large transients live in the 262MB f32 d_out region;
  // every one of them is dead before the final vocab GEMM rewrites d_out.
  char* w = (char*)d_ws;
  auto alloc = [&](size_t nbytes) { char* p = w; w += (nbytes + 255) & ~255ull; return p; };
  float* x     = (float*)alloc((size_t)BS_ * D_ * 4);
  float* h     = (float*)alloc((size_t)BS_ * D_ * 4);
  float* mbuf  = (float*)alloc((size_t)BS_ * D_ * 4);
  float* thr   = (float*)alloc((size_t)BS_ * 4);
  int*   counts = (int*)alloc(E_ * 4);
  int*   offp   = (int*)alloc((E_ + 1) * 4);
  int*   fill   = (int*)alloc(E_ * 4);
  int*   gi2    = (int*)alloc((size_t)BS_ * 2 * 4);
  float* gv2    = (float*)alloc((size_t)BS_ * 2 * 4);
  int*   toklist = (int*)alloc((size_t)NPAD_ * 4);
  float* gatel   = (float*)alloc((size_t)NPAD_ * 4);
  int*   explist = (int*)alloc((size_t)NPAD_ * 4);

  // d_out arena (scratch dead before final GEMM): sc 8.39M + h1 37.75M +
  // qi/ki 2x2.1M + qb/kbuf/vbuf/ao 4x4.19M = ~66.3MB < 262MB.
  char* oa = (char*)d_out;
  auto oalloc = [&](size_t nbytes) { char* p = oa; oa += (nbytes + 255) & ~255ull; return p; };
  float* sc    = (float*)oalloc((size_t)BS_ * S_ * 4);
  float* h1    = (float*)oalloc((size_t)NPAD_ * F_ * 4);
  float* qi    = (float*)oalloc((size_t)BS_ * 256 * 4);
  float* ki    = (float*)oalloc((size_t)BS_ * 256 * 4);
  float* qb    = (float*)oalloc((size_t)BS_ * D_ * 4);
  float* kbuf  = (float*)oalloc((size_t)BS_ * D_ * 4);
  float* vbuf  = (float*)oalloc((size_t)BS_ * D_ * 4);
  float* ao    = (float*)oalloc((size_t)BS_ * D_ * 4);

  embed_k<<<BS_, 256, 0, stream>>>(ids, tok, pos, x);

  for (int l = 0; l < L_; ++l) {
    const float* iqw_l = iqw + (size_t)l * D_ * 256;
    const float* iqb_l = iqb + (size_t)l * 256;
    const float* ikw_l = ikw + (size_t)l * D_ * 256;
    const float* ikb_l = ikb + (size_t)l * 256;
    const float* ihw_l = ihw + (size_t)l * HI_;
    const float* wq_l = wq + (size_t)l * D_ * D_, *bq_l = bq + (size_t)l * D_;
    const float* wk_l = wk + (size_t)l * D_ * D_, *bk_l = bk + (size_t)l * D_;
    const float* wv_l = wv + (size_t)l * D_ * D_, *bv_l = bv + (size_t)l * D_;
    const float* wo_l = wo + (size_t)l * D_ * D_, *bo_l = bo + (size_t)l * D_;
    const float* ew1_l = ew1 + (size_t)l * E_ * D_ * F_;
    const float* eb1_l = eb1 + (size_t)l * E_ * F_;
    const float* ew2_l = ew2 + (size_t)l * E_ * F_ * D_;
    const float* eb2_l = eb2 + (size_t)l * E_ * D_;

    ln_k<<<BS_, 256, 0, stream>>>(x, ln1g + l * D_, ln1b + l * D_, h);

    gemm_k<0><<<dim3(BS_ / 64, 256 / 64), 256, 0, stream>>>(h, iqw_l, iqb_l, nullptr, qi,
                                                            BS_, 256, D_, nullptr, nullptr, nullptr);
    gemm_k<0><<<dim3(BS_ / 64, 256 / 64), 256, 0, stream>>>(h, ikw_l, ikb_l, nullptr, ki,
                                                            BS_, 256, D_, nullptr, nullptr, nullptr);
    idxsc_k<<<BS_, 256, 0, stream>>>(qi, ki, ihw_l, sc);
    thr_k<<<BS_, 256, 0, stream>>>(sc, thr);

    gemm_k<0><<<dim3(BS_ / 64, D_ / 64), 256, 0, stream>>>(h, wq_l, bq_l, nullptr, qb,
                                                           BS_, D_, D_, nullptr, nullptr, nullptr);
    gemm_k<0><<<dim3(BS_ / 64, D_ / 64), 256, 0, stream>>>(h, wk_l, bk_l, nullptr, kbuf,
                                                           BS_, D_, D_, nullptr, nullptr, nullptr);
    gemm_k<0><<<dim3(BS_ / 64, D_ / 64), 256, 0, stream>>>(h, wv_l, bv_l, nullptr, vbuf,
                                                           BS_, D_, D_, nullptr, nullptr, nullptr);

    attn_k<<<B_ * H_ * S_, 64, 0, stream>>>(qb, kbuf, vbuf, sc, thr, ao);

    // x = x + ao @ wo + bo
    gemm_k<0><<<dim3(BS_ / 64, D_ / 64), 256, 0, stream>>>(ao, wo_l, bo_l, x, x,
                                                           BS_, D_, D_, nullptr, nullptr, nullptr);

    ln_k<<<BS_, 256, 0, stream>>>(x, ln2g + l * D_, ln2b + l * D_, mbuf);

    hipMemsetAsync(counts, 0, E_ * sizeof(int), stream);
    router_k<<<BS_ / 256, 256, 0, stream>>>(mbuf, rw + (size_t)l * D_ * E_, rb + (size_t)l * E_,
                                            counts, gi2, gv2);
    prefix_k<<<1, 64, 0, stream>>>(counts, offp, fill);
    initent_k<<<(NPAD_ + 255) / 256, 256, 0, stream>>>(offp, toklist, explist);
    fillent_k<<<BS_ / 256, 256, 0, stream>>>(gi2, gv2, offp, fill, toklist, gatel);

    gemm_k<1><<<dim3(CHUNKS_, F_ / 64), 256, 0, stream>>>(mbuf, ew1_l, eb1_l, nullptr, h1,
                                                          NPAD_, F_, D_, toklist, nullptr, explist);
    gemm_k<2><<<dim3(CHUNKS_, D_ / 64), 256, 0, stream>>>(h1, ew2_l, eb2_l, nullptr, x,
                                                          NPAD_, D_, F_, toklist, gatel, explist);
  }

  ln_k<<<BS_, 256, 0, stream>>>(x, lnfg, lnfb, h);
  // final vocab projection -> FLOAT32 output
  gemm_k<0><<<dim3(BS_ / 64, V_ / 64), 256, 0, stream>>>(h, outw, outbs, nullptr, y,
                                                         BS_, V_, D_, nullptr, nullptr, nullptr);
}